// Round 11
// baseline (177.974 us; speedup 1.0000x reference)
//
#include <hip/hip_runtime.h>
#include <hip/hip_bf16.h>

typedef __attribute__((ext_vector_type(8))) short bf16x8;
typedef __attribute__((ext_vector_type(4))) float f32x4;
typedef __attribute__((ext_vector_type(4))) unsigned short ushort4v;
typedef __attribute__((ext_vector_type(2))) unsigned uint2v;

__device__ __forceinline__ unsigned short f2bf(float f) {
  union { float f; unsigned u; } v; v.f = f;
  unsigned r = v.u + 0x7FFFu + ((v.u >> 16) & 1u);
  return (unsigned short)(r >> 16);
}

__device__ __forceinline__ unsigned pack_bf2(float lo, float hi) {
  __hip_bfloat162 h = __float22bfloat162_rn(make_float2(lo, hi));
  union { __hip_bfloat162 h; unsigned u; } cv; cv.h = h; return cv.u;
}

__device__ __forceinline__ void gll16(const void* g, void* l) {
  __builtin_amdgcn_global_load_lds((const __attribute__((address_space(1))) void*)g,
                                   (__attribute__((address_space(3))) void*)l, 16, 0, 0);
}

#define MFMA16(a, b, c) __builtin_amdgcn_mfma_f32_16x16x32_bf16((a), (b), (c), 0, 0, 0)

// ---------------------------------------------------------------- fused convert (x | w_qkv | w_proj)
__global__ void cvt3(const float* __restrict__ x, const float* __restrict__ wq,
                     const float* __restrict__ wp,
                     unsigned short* __restrict__ xb, unsigned short* __restrict__ wqb,
                     unsigned short* __restrict__ wpb) {
  int i = (blockIdx.x * blockDim.x + threadIdx.x) * 4;
  const float* s; unsigned short* d;
  if (i < 8388608)        { s = x  + i;                 d = xb  + i; }
  else if (i < 11534336)  { s = wq + (i - 8388608);     d = wqb + (i - 8388608); }
  else                    { s = wp + (i - 11534336);    d = wpb + (i - 11534336); }
  float4 f = *(const float4*)s;
  ushort4v r;
  r[0] = f2bf(f.x); r[1] = f2bf(f.y); r[2] = f2bf(f.z); r[3] = f2bf(f.w);
  *(ushort4v*)d = r;
}

// ---------------------------------------------------------------- persistent GEMM NT (r10, unchanged)
template<int EPI, int RPB>
__global__ __launch_bounds__(512, 1)
void gemmp(const unsigned short* __restrict__ A,
           const unsigned short* __restrict__ B,
           unsigned short* __restrict__ obf,
           float* __restrict__ of32,
           int M, int N, int K) {
  extern __shared__ unsigned short lds[];
  const int tid = threadIdx.x, wid = tid >> 6, lane = tid & 63;
  const int c = lane & 15, g = lane >> 4;
  const int wr = wid >> 1, wc = wid & 1;
  const int nbn = N >> 7;
  const int swzbid = (blockIdx.x & 7) * (gridDim.x >> 3) + (blockIdx.x >> 3);
  const int NT = K >> 6;
  const size_t rb = (size_t)K * 2;
  const int sw = (c & 7) << 4;

  const int srow = lane >> 3;
  const int sslot = (lane & 7) ^ srow;
  const char* Abase = (const char*)A;
  const char* Bbase = (const char*)B;

  auto stageA = [&](int m0p, int kt, int par) {
    const char* Agp = Abase + (size_t)(m0p + srow) * rb + sslot * 16 + kt * 128;
#pragma unroll
    for (int j = 0; j < 4; ++j) {
      int ch = wid * 4 + j;
      gll16(Agp + (size_t)(ch * 8) * rb, lds + par * 16384 + ch * 512);
    }
  };
  auto stageB = [&](int n0p, int kt, int par) {
    const char* Bgp = Bbase + (size_t)(n0p + srow) * rb + sslot * 16 + kt * 128;
#pragma unroll
    for (int j = 0; j < 2; ++j) {
      int ch = wid * 2 + j;
      gll16(Bgp + (size_t)(ch * 8) * rb, lds + 32768 + par * 8192 + ch * 512);
    }
  };

  f32x4 acc[4][4];
#pragma unroll
  for (int i = 0; i < 4; ++i)
#pragma unroll
    for (int j = 0; j < 4; ++j) acc[i][j] = f32x4{0.f, 0.f, 0.f, 0.f};

  int m0c = (swzbid / nbn) * 256, n0c = (swzbid % nbn) * 128;

  stageA(m0c, 0, 0); stageB(n0c, 0, 0); stageA(m0c, 1, 1); stageB(n0c, 1, 1);
  asm volatile("s_waitcnt vmcnt(4)" ::: "memory");
  __builtin_amdgcn_s_barrier();

  for (int p = 0; p < RPB; ++p) {
    int m0n = 0, n0n = 0;
    const bool morep = (p + 1 < RPB);
    if (morep) {
      int tile = (p + 1) * gridDim.x + swzbid;
      m0n = (tile / nbn) * 256; n0n = (tile % nbn) * 128;
    }
    for (int t = 0; t < NT; ++t) {
      const int par = t & 1;
      const char* Ac = (const char*)(lds + par * 16384);
      const char* Bc = (const char*)(lds + 32768 + par * 8192);
      bf16x8 af[4][2], bf0[2][2];
#pragma unroll
      for (int mi = 0; mi < 4; ++mi) {
        int arow = wr * 64 + mi * 16 + c;
#pragma unroll
        for (int kk = 0; kk < 2; ++kk)
          af[mi][kk] = *(const bf16x8*)(Ac + arow * 128 + ((kk * 64 + g * 16) ^ sw));
      }
#pragma unroll
      for (int ni = 0; ni < 2; ++ni) {
        int brow = wc * 64 + ni * 16 + c;
#pragma unroll
        for (int kk = 0; kk < 2; ++kk)
          bf0[ni][kk] = *(const bf16x8*)(Bc + brow * 128 + ((kk * 64 + g * 16) ^ sw));
      }
      {
        int tB = t + 1;
        if (tB < NT)      stageB(n0c, tB, tB & 1);
        else if (morep)   stageB(n0n, tB - NT, tB & 1);
      }
      __builtin_amdgcn_s_barrier();
      asm volatile("s_waitcnt lgkmcnt(0)" ::: "memory");
      __builtin_amdgcn_sched_barrier(0);
      __builtin_amdgcn_s_setprio(1);
#pragma unroll
      for (int kk = 0; kk < 2; ++kk)
#pragma unroll
        for (int mi = 0; mi < 4; ++mi)
#pragma unroll
          for (int ni = 0; ni < 2; ++ni)
            acc[mi][ni] = MFMA16(bf0[ni][kk], af[mi][kk], acc[mi][ni]);  // C^T
      __builtin_amdgcn_s_setprio(0);
      __builtin_amdgcn_s_barrier();
      bf16x8 bf1[2][2];
#pragma unroll
      for (int ni = 0; ni < 2; ++ni) {
        int brow = wc * 64 + (ni + 2) * 16 + c;
#pragma unroll
        for (int kk = 0; kk < 2; ++kk)
          bf1[ni][kk] = *(const bf16x8*)(Bc + brow * 128 + ((kk * 64 + g * 16) ^ sw));
      }
      bool okA;
      {
        int tA = t + 2;
        okA = (tA < NT) || morep;
        if (tA < NT)      stageA(m0c, tA, tA & 1);
        else if (morep)   stageA(m0n, tA - NT, tA & 1);
      }
      __builtin_amdgcn_s_barrier();
      asm volatile("s_waitcnt lgkmcnt(0)" ::: "memory");
      __builtin_amdgcn_sched_barrier(0);
      __builtin_amdgcn_s_setprio(1);
#pragma unroll
      for (int kk = 0; kk < 2; ++kk)
#pragma unroll
        for (int mi = 0; mi < 4; ++mi)
#pragma unroll
          for (int ni = 0; ni < 2; ++ni)
            acc[mi][ni + 2] = MFMA16(bf1[ni][kk], af[mi][kk], acc[mi][ni + 2]);
      __builtin_amdgcn_s_setprio(0);
      if (okA) { asm volatile("s_waitcnt vmcnt(4)" ::: "memory"); }
      else     { asm volatile("s_waitcnt vmcnt(0)" ::: "memory"); }
      __builtin_amdgcn_s_barrier();
    }

#pragma unroll
    for (int mi = 0; mi < 4; ++mi) {
      int mg = m0c + wr * 64 + mi * 16 + c;
      if (EPI == 0) {
        int bb = mg >> 11, tt = mg & 2047;
        size_t rowbase = ((size_t)(bb * 16) * 2048 + tt) * 64;
#pragma unroll
        for (int ni = 0; ni < 4; ++ni) {
          int ng = n0c + wc * 64 + ni * 16 + g * 4;
          int which = ng >> 10, rem = ng & 1023;
          int hh = rem >> 6, dd = rem & 63;
          uint2v pk;
          pk[0] = pack_bf2(acc[mi][ni][0], acc[mi][ni][1]);
          pk[1] = pack_bf2(acc[mi][ni][2], acc[mi][ni][3]);
          *(uint2v*)(obf + (size_t)which * 8388608u + rowbase + (size_t)hh * 131072 + dd) = pk;
        }
      } else {
        float* orow = of32 + (size_t)mg * N + n0c + wc * 64 + g * 4;
#pragma unroll
        for (int ni = 0; ni < 4; ++ni)
          *(f32x4*)(orow + ni * 16) = acc[mi][ni];
      }
    }
#pragma unroll
    for (int i = 0; i < 4; ++i)
#pragma unroll
      for (int j = 0; j < 4; ++j) acc[i][j] = f32x4{0.f, 0.f, 0.f, 0.f};
    m0c = m0n; n0c = n0n;
  }
}

// ---------------------------------------------------------------- flash attention, QBLK=128 (4 waves x 32 rows)
__global__ __launch_bounds__(256, 4)
void attn_fwd(const unsigned short* __restrict__ qb,
              const unsigned short* __restrict__ kb,
              const unsigned short* __restrict__ vb,
              unsigned short* __restrict__ yb) {
  __shared__ unsigned short Kt[64 * 64];       // [kv][d], XOR-swizzled 16B granules
  __shared__ unsigned short Vt[64 * 64];       // [d][kv], swizzled
  __shared__ unsigned short Pl[4 * 32 * 72];   // per-wave P [q=32][kv=64], rows padded to 72
  const int tid = threadIdx.x, w = tid >> 6, lane = tid & 63;
  const int c = lane & 15, g = lane >> 4;
  const int bh = blockIdx.x & 63;              // xcd = blockIdx%8 = bh%8 -> per-head L2 affinity
  const int qt = 15 - (blockIdx.x >> 6);       // long blocks first
  const int q0 = qt * 128;
  const int b = bh >> 4, h = bh & 15;
  const size_t hb = (size_t)bh * 131072;
  const float GAM = 0.125f * 1.44269504089f;

  // Q fragments for both 16-row subs, register-resident
  bf16x8 qf[2][2];
#pragma unroll
  for (int s = 0; s < 2; ++s) {
    const unsigned short* qp = qb + hb + (size_t)(q0 + w * 32 + s * 16 + c) * 64;
    qf[s][0] = *(const bf16x8*)(qp + g * 8);
    qf[s][1] = *(const bf16x8*)(qp + 32 + g * 8);
  }

  f32x4 yacc[2][4];
#pragma unroll
  for (int s = 0; s < 2; ++s)
#pragma unroll
    for (int i = 0; i < 4; ++i) yacc[s][i] = f32x4{0.f, 0.f, 0.f, 0.f};
  float mrun[2] = {-1e30f, -1e30f};
  float lsum[2] = {0.f, 0.f};
  unsigned short* pw = Pl + w * (32 * 72);

  const int nkv = 2 * qt + 2;
  for (int kv = 0; kv < nkv; ++kv) {
    const int kv0 = kv * 64;
    if (kv) __syncthreads();
    // --- stage K via global_load_lds, pre-swizzled source
#pragma unroll
    for (int r = 0; r < 2; ++r) {
      int chunk = w * 2 + r;
      int row = chunk * 8 + (lane >> 3);
      int bo = (lane & 7) * 16;
      int sbo = bo ^ ((row & 7) << 4);
      gll16((const char*)(kb + hb + (size_t)(kv0 + row) * 64) + sbo, Kt + chunk * 512);
    }
    // --- stage V transposed (reg-staged, packed b32 swizzled writes)
    {
      int kv2 = (lane & 31) * 2;
      int dblk = w * 16 + (lane >> 5) * 8;
      const unsigned short* vp = vb + hb + (size_t)(kv0 + kv2) * 64 + dblk;
      bf16x8 r0 = *(const bf16x8*)(vp);
      bf16x8 r1 = *(const bf16x8*)(vp + 64);
#pragma unroll
      for (int i = 0; i < 8; ++i) {
        int d = dblk + i;
        unsigned pk2 = ((unsigned)(unsigned short)r0[i]) | (((unsigned)(unsigned short)r1[i]) << 16);
        *(unsigned*)(Vt + d * 64 + (kv2 ^ ((d & 7) << 3))) = pk2;
      }
    }
    __syncthreads();

#pragma unroll
    for (int s = 0; s < 2; ++s) {
      const int rowmin = q0 + w * 32 + s * 16;      // wave-uniform
      if (kv0 > rowmin + 15) continue;              // sub fully masked: skip (uniform)
      // --- S^T = K @ Q^T
      f32x4 sacc[4];
#pragma unroll
      for (int nt = 0; nt < 4; ++nt) sacc[nt] = f32x4{0.f, 0.f, 0.f, 0.f};
#pragma unroll
      for (int kk = 0; kk < 2; ++kk)
#pragma unroll
        for (int nt = 0; nt < 4; ++nt) {
          int row = nt * 16 + c;
          bf16x8 kf = *(const bf16x8*)(Kt + row * 64 + ((kk * 32 + g * 8) ^ ((row & 7) << 3)));
          sacc[nt] = MFMA16(kf, qf[s][kk], sacc[nt]);
        }
      // --- causal mask (only when tile straddles the diagonal; uniform)
      if (kv0 + 63 > rowmin) {
        int ql = rowmin + c;
#pragma unroll
        for (int nt = 0; nt < 4; ++nt)
#pragma unroll
          for (int r = 0; r < 4; ++r)
            if (kv0 + nt * 16 + g * 4 + r > ql) sacc[nt][r] = -1e30f;
      }
      // --- row max
      float m0 = -1e30f;
#pragma unroll
      for (int nt = 0; nt < 4; ++nt) {
        float a = fmaxf(fmaxf(sacc[nt][0], sacc[nt][1]), fmaxf(sacc[nt][2], sacc[nt][3]));
        m0 = fmaxf(m0, a);
      }
      m0 = fmaxf(m0, __shfl_xor(m0, 16));
      m0 = fmaxf(m0, __shfl_xor(m0, 32));
      // --- deferred rescale
      if (__any(m0 > mrun[s] + 32.0f)) {
        float mnew = fmaxf(mrun[s], m0);
        float corr = __builtin_amdgcn_exp2f(GAM * (mrun[s] - mnew));
        lsum[s] *= corr;
#pragma unroll
        for (int dt = 0; dt < 4; ++dt) yacc[s][dt] *= corr;
        mrun[s] = mnew;
      }
      // --- P = exp2(GAM*s - GAM*mrun)
      float bexp = -GAM * mrun[s];
      float psum = 0.f;
#pragma unroll
      for (int nt = 0; nt < 4; ++nt) {
        float p0 = __builtin_amdgcn_exp2f(fmaf(sacc[nt][0], GAM, bexp));
        float p1 = __builtin_amdgcn_exp2f(fmaf(sacc[nt][1], GAM, bexp));
        float p2 = __builtin_amdgcn_exp2f(fmaf(sacc[nt][2], GAM, bexp));
        float p3 = __builtin_amdgcn_exp2f(fmaf(sacc[nt][3], GAM, bexp));
        psum += (p0 + p1) + (p2 + p3);
        uint2v pkv;
        pkv[0] = pack_bf2(p0, p1);
        pkv[1] = pack_bf2(p2, p3);
        *(uint2v*)(pw + (s * 16 + c) * 72 + nt * 16 + g * 4) = pkv;
      }
      lsum[s] += psum;
      // --- Y^T += V^T @ P^T
#pragma unroll
      for (int kk = 0; kk < 2; ++kk) {
        bf16x8 pb = *(const bf16x8*)(pw + (s * 16 + c) * 72 + kk * 32 + g * 8);
#pragma unroll
        for (int dt = 0; dt < 4; ++dt) {
          int n = dt * 16 + c;
          bf16x8 vf = *(const bf16x8*)(Vt + n * 64 + ((kk * 32 + g * 8) ^ ((n & 7) << 3)));
          yacc[s][dt] = MFMA16(vf, pb, yacc[s][dt]);
        }
      }
    }
  }

  // --- epilogue per sub
#pragma unroll
  for (int s = 0; s < 2; ++s) {
    float ls = lsum[s];
    ls += __shfl_xor(ls, 16);
    ls += __shfl_xor(ls, 32);
    float inv = 1.0f / ls;
    int row = q0 + w * 32 + s * 16 + c;
    unsigned short* yp = yb + ((size_t)(b * 2048 + row)) * 1024 + h * 64;
#pragma unroll
    for (int dt = 0; dt < 4; ++dt) {
      uint2v pkv;
      pkv[0] = pack_bf2(yacc[s][dt][0] * inv, yacc[s][dt][1] * inv);
      pkv[1] = pack_bf2(yacc[s][dt][2] * inv, yacc[s][dt][3] * inv);
      *(uint2v*)(yp + dt * 16 + g * 4) = pkv;
    }
  }
}

// ---------------------------------------------------------------- launch
extern "C" void kernel_launch(void* const* d_in, const int* in_sizes, int n_in,
                              void* d_out, int out_size, void* d_ws, size_t ws_size,
                              hipStream_t stream) {
  const float* x     = (const float*)d_in[0];
  const float* wqkv  = (const float*)d_in[1];
  const float* wproj = (const float*)d_in[2];
  float* out = (float*)d_out;

  unsigned short* ws     = (unsigned short*)d_ws;
  unsigned short* xb     = ws;                       // 8388608
  unsigned short* wqkvb  = xb + 8388608;             // 3145728
  unsigned short* wprojb = wqkvb + 3145728;          // 1048576
  unsigned short* qkvb   = wprojb + 1048576;         // 3 * 8388608 (q,k,v)
  unsigned short* yb     = qkvb + 3 * 8388608;       // 8388608

  cvt3<<<12288, 256, 0, stream>>>(x, wqkv, wproj, xb, wqkvb, wprojb);

  gemmp<0, 3><<<256, 512, 98304, stream>>>(xb, wqkvb, qkvb, nullptr, 8192, 3072, 1024);
  attn_fwd<<<1024, 256, 0, stream>>>(qkvb, qkvb + 8388608, qkvb + 2 * 8388608, yb);
  gemmp<1, 1><<<256, 512, 98304, stream>>>(yb, wprojb, nullptr, out, 8192, 1024, 1024);
}

// Round 13
// 172.830 us; speedup vs baseline: 1.0298x; 1.0298x over previous
//
#include <hip/hip_runtime.h>
#include <hip/hip_bf16.h>

typedef __attribute__((ext_vector_type(8))) short bf16x8;
typedef __attribute__((ext_vector_type(4))) float f32x4;
typedef __attribute__((ext_vector_type(4))) unsigned short ushort4v;
typedef __attribute__((ext_vector_type(2))) unsigned uint2v;

__device__ __forceinline__ unsigned short f2bf(float f) {
  union { float f; unsigned u; } v; v.f = f;
  unsigned r = v.u + 0x7FFFu + ((v.u >> 16) & 1u);
  return (unsigned short)(r >> 16);
}

__device__ __forceinline__ unsigned pack_bf2(float lo, float hi) {
  __hip_bfloat162 h = __float22bfloat162_rn(make_float2(lo, hi));
  union { __hip_bfloat162 h; unsigned u; } cv; cv.h = h; return cv.u;
}

__device__ __forceinline__ void gll16(const void* g, void* l) {
  __builtin_amdgcn_global_load_lds((const __attribute__((address_space(1))) void*)g,
                                   (__attribute__((address_space(3))) void*)l, 16, 0, 0);
}

#define MFMA16(a, b, c) __builtin_amdgcn_mfma_f32_16x16x32_bf16((a), (b), (c), 0, 0, 0)

// ---------------------------------------------------------------- fused convert (x | w_qkv | w_proj)
__global__ void cvt3(const float* __restrict__ x, const float* __restrict__ wq,
                     const float* __restrict__ wp,
                     unsigned short* __restrict__ xb, unsigned short* __restrict__ wqb,
                     unsigned short* __restrict__ wpb) {
  int i = (blockIdx.x * blockDim.x + threadIdx.x) * 4;
  const float* s; unsigned short* d;
  if (i < 8388608)        { s = x  + i;                 d = xb  + i; }
  else if (i < 11534336)  { s = wq + (i - 8388608);     d = wqb + (i - 8388608); }
  else                    { s = wp + (i - 11534336);    d = wpb + (i - 11534336); }
  float4 f = *(const float4*)s;
  ushort4v r;
  r[0] = f2bf(f.x); r[1] = f2bf(f.y); r[2] = f2bf(f.z); r[3] = f2bf(f.w);
  *(ushort4v*)d = r;
}

// ---------------------------------------------------------------- GEMM NT, BK=32, multi-block/CU
// MIF=8: BM=256, MIF=4: BM=128. BN=128. 256 thr / 4 waves (2M x 2N),
// wave tile (MIF*16) x 64. 3-deep LDS ring: buf b at b*(BM+128)*64 bytes.
// Loads/thread/stage: A = MIF/2, B = 2 -> 6 (MIF=8) or 4 (MIF=4).
// Ledger: iter t stages t+2; end-of-t drain to vmcnt(loads) completes t+1;
// reads finish (lgkmcnt 0) before the barrier so ring reuse is race-free.
// Swizzle (64B rows, 4x16B slots): key(row) = (row ^ (row>>2)) & 3; staged via
// pre-swizzled global source; read col = (g ^ key(c)) * 16.
template<int EPI, int MIF>
__global__ __launch_bounds__(256, 2)
void gemmf(const unsigned short* __restrict__ A,
           const unsigned short* __restrict__ B,
           unsigned short* __restrict__ obf,
           float* __restrict__ of32,
           int M, int N, int K) {
  extern __shared__ char lds[];
  constexpr int BM = MIF * 32;
  constexpr int BUFB = (BM + 128) * 64;    // bytes per ring slot
  const int tid = threadIdx.x, wid = tid >> 6, lane = tid & 63;
  const int c = lane & 15, g = lane >> 4;
  const int wm = wid >> 1, wn = wid & 1;
  const int nbn = N >> 7;
  const int wg = (blockIdx.x & 7) * (gridDim.x >> 3) + (blockIdx.x >> 3);  // XCD swizzle
  const int m0 = (wg / nbn) * BM, n0 = (wg % nbn) * 128;
  const int NT = K >> 5;                    // K-tiles (K=1024 -> 32)
  const size_t rb = (size_t)K * 2;          // global row bytes
  const int rk = (c ^ (c >> 2)) & 3;        // per-lane read XOR key

  // staging: lane covers (row16 = lane>>2 within chunk, slot = lane&3), pre-swizzled src
  const int lrow = lane >> 2;
  const int lslot = (lane & 3) ^ (((lane >> 2) ^ (lane >> 4)) & 3);
  const char* Ab = (const char*)A + (size_t)m0 * rb + (size_t)lrow * rb + lslot * 16;
  const char* Bb = (const char*)B + (size_t)n0 * rb + (size_t)lrow * rb + lslot * 16;

  auto stage = [&](int t, int buf) {
    char* base = lds + buf * BUFB;
#pragma unroll
    for (int j = 0; j < MIF / 2; ++j) {     // A: BM/16 chunks of 16 rows, wave does MIF/2
      int ch = wid * (MIF / 2) + j;
      gll16(Ab + (size_t)(ch * 16) * rb + t * 64, base + ch * 1024);
    }
#pragma unroll
    for (int j = 0; j < 2; ++j) {           // B: 8 chunks, wave does 2
      int ch = wid * 2 + j;
      gll16(Bb + (size_t)(ch * 16) * rb + t * 64, base + BM * 64 + ch * 1024);
    }
  };

  f32x4 acc[MIF][4];
#pragma unroll
  for (int i = 0; i < MIF; ++i)
#pragma unroll
    for (int j = 0; j < 4; ++j) acc[i][j] = f32x4{0.f, 0.f, 0.f, 0.f};

  // prologue: stage tiles 0,1 (2*loads outstanding); drain tile 0
  stage(0, 0); stage(1, 1);
  if constexpr (MIF == 8) { asm volatile("s_waitcnt vmcnt(6)" ::: "memory"); }
  else                    { asm volatile("s_waitcnt vmcnt(4)" ::: "memory"); }
  __builtin_amdgcn_s_barrier();

  const int col = ((g ^ rk) << 4);
  for (int t = 0; t < NT; ++t) {
    const char* base = lds + (t % 3) * BUFB;
    bf16x8 af[MIF], bfr[4];
#pragma unroll
    for (int mi = 0; mi < MIF; ++mi) {
      int arow = wm * (MIF * 16) + mi * 16 + c;   // per-wave tile = MIF*16 rows
      af[mi] = *(const bf16x8*)(base + arow * 64 + col);
    }
#pragma unroll
    for (int ni = 0; ni < 4; ++ni) {
      int brow = wn * 64 + ni * 16 + c;
      bfr[ni] = *(const bf16x8*)(base + BM * 64 + brow * 64 + col);
    }
    const bool more = (t + 2 < NT);
    if (more) stage(t + 2, (t + 2) % 3);
    asm volatile("s_waitcnt lgkmcnt(0)" ::: "memory");
    __builtin_amdgcn_sched_barrier(0);
    __builtin_amdgcn_s_setprio(1);
#pragma unroll
    for (int mi = 0; mi < MIF; ++mi)
#pragma unroll
      for (int ni = 0; ni < 4; ++ni)
        acc[mi][ni] = MFMA16(bfr[ni], af[mi], acc[mi][ni]);   // swapped: acc = C^T
    __builtin_amdgcn_s_setprio(0);
    if (more) {
      if constexpr (MIF == 8) { asm volatile("s_waitcnt vmcnt(6)" ::: "memory"); }
      else                    { asm volatile("s_waitcnt vmcnt(4)" ::: "memory"); }
    } else {
      asm volatile("s_waitcnt vmcnt(0)" ::: "memory");
    }
    __builtin_amdgcn_s_barrier();
  }

  // ---- epilogue: C^T regs -> row mg per lane (c), 4 consecutive ng per acc reg
#pragma unroll
  for (int mi = 0; mi < MIF; ++mi) {
    int mg = m0 + wm * (MIF * 16) + mi * 16 + c;
    if (EPI == 0) {
      int bb = mg >> 11, tt = mg & 2047;
      size_t rowbase = ((size_t)(bb * 16) * 2048 + tt) * 64;
#pragma unroll
      for (int ni = 0; ni < 4; ++ni) {
        int ng = n0 + wn * 64 + ni * 16 + g * 4;
        int which = ng >> 10, rem = ng & 1023;
        int hh = rem >> 6, dd = rem & 63;
        uint2v pk;
        pk[0] = pack_bf2(acc[mi][ni][0], acc[mi][ni][1]);
        pk[1] = pack_bf2(acc[mi][ni][2], acc[mi][ni][3]);
        *(uint2v*)(obf + (size_t)which * 8388608u + rowbase + (size_t)hh * 131072 + dd) = pk;
      }
    } else {
      float* orow = of32 + (size_t)mg * N + n0 + wn * 64 + g * 4;
#pragma unroll
      for (int ni = 0; ni < 4; ++ni)
        *(f32x4*)(orow + ni * 16) = acc[mi][ni];
    }
  }
}

// ---------------------------------------------------------------- flash attention (r10 exact, known-good 77us)
__global__ __launch_bounds__(256, 6)
void attn_fwd(const unsigned short* __restrict__ qb,
              const unsigned short* __restrict__ kb,
              const unsigned short* __restrict__ vb,
              unsigned short* __restrict__ yb) {
  __shared__ unsigned short Kt[64 * 64];
  __shared__ unsigned short Vt[64 * 64];
  __shared__ unsigned short Pl[4 * 16 * 72];
  const int tid = threadIdx.x, w = tid >> 6, lane = tid & 63;
  const int c = lane & 15, g = lane >> 4;
  const int bh = blockIdx.x & 63;
  const int qt = 31 - (blockIdx.x >> 6);
  const int q0 = qt * 64;
  const int b = bh >> 4, h = bh & 15;
  const size_t hb = (size_t)bh * 131072;
  const float GAM = 0.125f * 1.44269504089f;

  const unsigned short* qp = qb + hb + (size_t)(q0 + w * 16 + c) * 64;
  bf16x8 qf0 = *(const bf16x8*)(qp + g * 8);
  bf16x8 qf1 = *(const bf16x8*)(qp + 32 + g * 8);

  f32x4 yacc[4];
#pragma unroll
  for (int i = 0; i < 4; ++i) yacc[i] = f32x4{0.f, 0.f, 0.f, 0.f};
  float mrun = -1e30f, lsum = 0.f;
  unsigned short* pw = Pl + w * (16 * 72);

  for (int kv = 0; kv <= qt; ++kv) {
    const int kv0 = kv * 64;
    const bool diag = (kv == qt);
    if (kv) __syncthreads();
#pragma unroll
    for (int r = 0; r < 2; ++r) {
      int chunk = w * 2 + r;
      int row = chunk * 8 + (lane >> 3);
      int bo = (lane & 7) * 16;
      int sbo = bo ^ ((row & 7) << 4);
      gll16((const char*)(kb + hb + (size_t)(kv0 + row) * 64) + sbo, Kt + chunk * 512);
    }
    {
      int kv2 = (lane & 31) * 2;
      int dblk = w * 16 + (lane >> 5) * 8;
      const unsigned short* vp = vb + hb + (size_t)(kv0 + kv2) * 64 + dblk;
      bf16x8 r0 = *(const bf16x8*)(vp);
      bf16x8 r1 = *(const bf16x8*)(vp + 64);
#pragma unroll
      for (int i = 0; i < 8; ++i) {
        int d = dblk + i;
        unsigned pk2 = ((unsigned)(unsigned short)r0[i]) | (((unsigned)(unsigned short)r1[i]) << 16);
        *(unsigned*)(Vt + d * 64 + (kv2 ^ ((d & 7) << 3))) = pk2;
      }
    }
    __syncthreads();

    f32x4 sacc[4];
#pragma unroll
    for (int nt = 0; nt < 4; ++nt) sacc[nt] = f32x4{0.f, 0.f, 0.f, 0.f};
#pragma unroll
    for (int kk = 0; kk < 2; ++kk)
#pragma unroll
      for (int nt = 0; nt < 4; ++nt) {
        int row = nt * 16 + c;
        bf16x8 kf = *(const bf16x8*)(Kt + row * 64 + ((kk * 32 + g * 8) ^ ((row & 7) << 3)));
        sacc[nt] = MFMA16(kf, (kk ? qf1 : qf0), sacc[nt]);
      }

    if (diag) {
      int ql = w * 16 + c;
#pragma unroll
      for (int nt = 0; nt < 4; ++nt)
#pragma unroll
        for (int r = 0; r < 4; ++r)
          if (nt * 16 + g * 4 + r > ql) sacc[nt][r] = -1e30f;
    }

    float m0 = -1e30f;
#pragma unroll
    for (int nt = 0; nt < 4; ++nt) {
      float a = fmaxf(fmaxf(sacc[nt][0], sacc[nt][1]), fmaxf(sacc[nt][2], sacc[nt][3]));
      m0 = fmaxf(m0, a);
    }
    m0 = fmaxf(m0, __shfl_xor(m0, 16));
    m0 = fmaxf(m0, __shfl_xor(m0, 32));

    if (__any(m0 > mrun + 32.0f)) {
      float mnew = fmaxf(mrun, m0);
      float corr = __builtin_amdgcn_exp2f(GAM * (mrun - mnew));
      lsum *= corr;
#pragma unroll
      for (int dt = 0; dt < 4; ++dt) yacc[dt] *= corr;
      mrun = mnew;
    }

    float bexp = -GAM * mrun;
    float psum = 0.f;
#pragma unroll
    for (int nt = 0; nt < 4; ++nt) {
      float p0 = __builtin_amdgcn_exp2f(fmaf(sacc[nt][0], GAM, bexp));
      float p1 = __builtin_amdgcn_exp2f(fmaf(sacc[nt][1], GAM, bexp));
      float p2 = __builtin_amdgcn_exp2f(fmaf(sacc[nt][2], GAM, bexp));
      float p3 = __builtin_amdgcn_exp2f(fmaf(sacc[nt][3], GAM, bexp));
      psum += (p0 + p1) + (p2 + p3);
      uint2v pkv;
      pkv[0] = pack_bf2(p0, p1);
      pkv[1] = pack_bf2(p2, p3);
      *(uint2v*)(pw + c * 72 + nt * 16 + g * 4) = pkv;
    }
    lsum += psum;

#pragma unroll
    for (int kk = 0; kk < 2; ++kk) {
      bf16x8 pb = *(const bf16x8*)(pw + c * 72 + kk * 32 + g * 8);
#pragma unroll
      for (int dt = 0; dt < 4; ++dt) {
        int n = dt * 16 + c;
        bf16x8 vf = *(const bf16x8*)(Vt + n * 64 + ((kk * 32 + g * 8) ^ ((n & 7) << 3)));
        yacc[dt] = MFMA16(vf, pb, yacc[dt]);
      }
    }
  }

  lsum += __shfl_xor(lsum, 16);
  lsum += __shfl_xor(lsum, 32);
  float inv = 1.0f / lsum;
  int row = q0 + w * 16 + c;
  unsigned short* yp = yb + ((size_t)(b * 2048 + row)) * 1024 + h * 64;
#pragma unroll
  for (int dt = 0; dt < 4; ++dt) {
    uint2v pkv;
    pkv[0] = pack_bf2(yacc[dt][0] * inv, yacc[dt][1] * inv);
    pkv[1] = pack_bf2(yacc[dt][2] * inv, yacc[dt][3] * inv);
    *(uint2v*)(yp + dt * 16 + g * 4) = pkv;
  }
}

// ---------------------------------------------------------------- launch
extern "C" void kernel_launch(void* const* d_in, const int* in_sizes, int n_in,
                              void* d_out, int out_size, void* d_ws, size_t ws_size,
                              hipStream_t stream) {
  const float* x     = (const float*)d_in[0];
  const float* wqkv  = (const float*)d_in[1];
  const float* wproj = (const float*)d_in[2];
  float* out = (float*)d_out;

  unsigned short* ws     = (unsigned short*)d_ws;
  unsigned short* xb     = ws;                       // 8388608
  unsigned short* wqkvb  = xb + 8388608;             // 3145728
  unsigned short* wprojb = wqkvb + 3145728;          // 1048576
  unsigned short* qkvb   = wprojb + 1048576;         // 3 * 8388608 (q,k,v)
  unsigned short* yb     = qkvb + 3 * 8388608;       // 8388608

  cvt3<<<12288, 256, 0, stream>>>(x, wqkv, wproj, xb, wqkvb, wprojb);

  // gemm1: BM=256 BN=128 BK=32, 3-ring 72KB LDS, grid 768 (= tiles, 2 blocks/CU by LDS)
  gemmf<0, 8><<<768, 256, 73728, stream>>>(xb, wqkvb, qkvb, nullptr, 8192, 3072, 1024);
  attn_fwd<<<2048, 256, 0, stream>>>(qkvb, qkvb + 8388608, qkvb + 2 * 8388608, yb);
  // gemm2: BM=128 BN=128, 48KB LDS, grid 512 (= tiles)
  gemmf<1, 4><<<512, 256, 49152, stream>>>(yb, wprojb, nullptr, out, 8192, 1024, 1024);
}